// Round 2
// baseline (615.916 us; speedup 1.0000x reference)
//
#include <hip/hip_runtime.h>
#include <stdint.h>

#define B_BATCH 8
#define S_SEQ   4096
#define D_DIM   1024
#define H_DIM   2048
#define M_TOK   (B_BATCH * S_SEQ)   // 32768
#define MAXK    64
#define NSPLIT  2                   // pl slices (H halves); one half per XCD parity

typedef unsigned int u32;
typedef unsigned short u16;
typedef unsigned long long u64;
typedef __attribute__((ext_vector_type(8))) short short8;   // 8 bf16 (4 VGPRs)
typedef __attribute__((ext_vector_type(4))) float f32x4;

#define GLOBAL_AS __attribute__((address_space(1)))
#define LDS_AS    __attribute__((address_space(3)))

// ---------------- JAX threefry2x32 (20 rounds), partitionable mode ----------------

#define TF_ROUND(x0, x1, r) { x0 += x1; x1 = ((x1 << r) | (x1 >> (32 - r))); x1 ^= x0; }

__device__ __forceinline__ void tf2x32(u32 k0, u32 k1, u32 x0, u32 x1, u32& o0, u32& o1) {
  u32 k2 = k0 ^ k1 ^ 0x1BD11BDAu;
  x0 += k0; x1 += k1;
  TF_ROUND(x0, x1, 13) TF_ROUND(x0, x1, 15) TF_ROUND(x0, x1, 26) TF_ROUND(x0, x1, 6)
  x0 += k1; x1 += k2 + 1u;
  TF_ROUND(x0, x1, 17) TF_ROUND(x0, x1, 29) TF_ROUND(x0, x1, 16) TF_ROUND(x0, x1, 24)
  x0 += k2; x1 += k0 + 2u;
  TF_ROUND(x0, x1, 13) TF_ROUND(x0, x1, 15) TF_ROUND(x0, x1, 26) TF_ROUND(x0, x1, 6)
  x0 += k0; x1 += k1 + 3u;
  TF_ROUND(x0, x1, 17) TF_ROUND(x0, x1, 29) TF_ROUND(x0, x1, 16) TF_ROUND(x0, x1, 24)
  x0 += k1; x1 += k2 + 4u;
  TF_ROUND(x0, x1, 13) TF_ROUND(x0, x1, 15) TF_ROUND(x0, x1, 26) TF_ROUND(x0, x1, 6)
  x0 += k2; x1 += k0 + 5u;
  o0 = x0; o1 = x1;
}

__device__ __forceinline__ void jax_subkeys(u32& r1a, u32& r1b, u32& r2a, u32& r2b) {
  tf2x32(0u, 42u, 0u, 0u, r1a, r1b);
  tf2x32(0u, 42u, 0u, 1u, r2a, r2b);
}

__device__ __forceinline__ u32 jax_bits32(u32 ka, u32 kb, u32 i) {
  u32 o0, o1;
  tf2x32(ka, kb, 0u, i, o0, o1);
  return o0 ^ o1;
}

__device__ __forceinline__ float jax_uniform_from_bits(u32 bits) {
  float f = __uint_as_float((bits >> 9) | 0x3f800000u) - 1.0f;
  float r = f + 1e-8f;
  return fmaxf(1e-8f, r);
}

__device__ __forceinline__ float gumbel_from_bits(u32 bits) {
  float u = jax_uniform_from_bits(bits);
  return -logf(-logf(u));
}

__device__ __forceinline__ u32 ordf(float v) {
  u32 b = __float_as_uint(v);
  return (b & 0x80000000u) ? ~b : (b | 0x80000000u);
}

__device__ __forceinline__ u64 shflx64(u64 v, int m) {
  unsigned lo = (unsigned)v, hi = (unsigned)(v >> 32);
  lo = (unsigned)__shfl_xor((int)lo, m);
  hi = (unsigned)__shfl_xor((int)hi, m);
  return ((u64)hi << 32) | lo;
}

// ---------------- bf16 split helpers ----------------

__device__ __forceinline__ u16 f2bf_rn(float x) {
  u32 u = __float_as_uint(x);
  u32 r = u + 0x7fffu + ((u >> 16) & 1u);
  return (u16)(r >> 16);
}

__device__ __forceinline__ void split1(float x, u16& h, u16& lo) {
  h = f2bf_rn(x);
  float hf = __uint_as_float(((u32)h) << 16);
  lo = f2bf_rn(x - hf);
}

// ---------------- fused prep: A split (grid-stride) + W1 transpose/split ----------------
// blocks [0,2048): A split, 16 float4/thread grid-stride (G11/G13: deep MLP, no tail).
// blocks [2048,4096): W1 [D][H] -> W1t [H][D] hi/lo split (32x32 LDS transpose tiles).

#define PREP_A_BLOCKS 2048

__global__ __launch_bounds__(256) void prep_kernel(const float* __restrict__ x,
                                                   u16* __restrict__ hi,
                                                   u16* __restrict__ lo,
                                                   const float* __restrict__ W1,
                                                   u16* __restrict__ bhi,
                                                   u16* __restrict__ blo) {
  const int b = blockIdx.x;
  if (b < PREP_A_BLOCKS) {
    #pragma unroll
    for (int itr = 0; itr < 16; ++itr) {
      const size_t i = ((size_t)itr * PREP_A_BLOCKS * 256 + (size_t)b * 256 + threadIdx.x) * 4;
      float4 v = *(const float4*)(x + i);
      u16 h0, h1, h2, h3, l0, l1, l2, l3;
      split1(v.x, h0, l0); split1(v.y, h1, l1); split1(v.z, h2, l2); split1(v.w, h3, l3);
      u64 hv = (u64)h0 | ((u64)h1 << 16) | ((u64)h2 << 32) | ((u64)h3 << 48);
      u64 lv = (u64)l0 | ((u64)l1 << 16) | ((u64)l2 << 32) | ((u64)l3 << 48);
      *(u64*)(hi + i) = hv;
      *(u64*)(lo + i) = lv;
    }
  } else {
    __shared__ float tile[32][33];
    const int bid2 = b - PREP_A_BLOCKS;
    const int tx = threadIdx.x & 31, ty = threadIdx.x >> 5;  // ty 0..7
    const int n0 = (bid2 & 63) * 32, k0 = (bid2 >> 6) * 32;
    #pragma unroll
    for (int r = 0; r < 4; ++r)
      tile[ty + r * 8][tx] = W1[(size_t)(k0 + ty + r * 8) * H_DIM + n0 + tx];
    __syncthreads();
    #pragma unroll
    for (int r = 0; r < 4; ++r) {
      const int n = n0 + ty + r * 8, k = k0 + tx;
      u16 h, l;
      split1(tile[tx][ty + r * 8], h, l);
      bhi[(size_t)n * D_DIM + k] = h;
      blo[(size_t)n * D_DIM + k] = l;
    }
  }
}

// ---------------- K2: bf16x3 MFMA scorer, 256x256 tile, 8-phase counted-vmcnt ----------------
// (unchanged from R1: 8 waves 2m x 4n, BK=32, 2x64KB LDS dbuf + 4KB red, counted
// vmcnt(10)/(8), setprio around MFMA clusters, XOR chunk swizzle both sides.)

__device__ __forceinline__ void stage16(const u16* g, u16* l) {
  __builtin_amdgcn_global_load_lds((const GLOBAL_AS u32*)g, (LDS_AS u32*)l, 16, 0, 0);
}

#define WAITV(N) asm volatile("s_waitcnt vmcnt(" #N ")" ::: "memory")
#define FENCE()  asm volatile("" ::: "memory")

__global__ __launch_bounds__(512, 2) void scorer_mfma256(
    const u16* __restrict__ Ahi, const u16* __restrict__ Alo,
    const u16* __restrict__ Bhi, const u16* __restrict__ Blo,
    const float* __restrict__ b1, const float* __restrict__ W2,
    float* __restrict__ pl) {
  extern __shared__ u16 smem[];                 // 2 x 32768 elems + 2048 elems (red)
  float* red = (float*)(smem + 65536);          // [256 rows][4 wn] f32

  const int tid = threadIdx.x;
  const int w = tid >> 6, l = tid & 63;
  const int wm = w >> 2, wn = w & 3;

  const int b = blockIdx.x;
  const int xcd = b & 7;
  const int nyb = xcd & 1;                      // H half for this XCD parity
  const int m0 = ((b >> 3) * 4 + (xcd >> 1)) * 256;

  // ---- staging constants (one stage16 per thread per unit) ----
  const int sig = w * 16 + (l >> 2);            // LDS row-slot written by this lane
  const int swz = ((l & 3) ^ ((sig >> 1) & 3)) << 3;  // pre-swizzled k-chunk (elems)
  const size_t aoffE = (size_t)(m0 + sig + (sig & 64)) * D_DIM + swz;  // rows 0-63|128-191
  const size_t aoffL = aoffE + (size_t)64 * D_DIM;                      // rows 64-127|192-255
  const size_t boff0 = (size_t)(nyb * 1024 + sig) * D_DIM + swz;        // B rows 0-127
  const size_t boff1 = boff0 + (size_t)128 * D_DIM;                     // B rows 128-255
  u16* const ldsw = smem + w * 512;             // per-wave (uniform) dest within a unit

#define ST_AhiE(T) stage16(Ahi + aoffE + (size_t)((((T) & 31) << 5)), ldsw + (((T) & 1) << 15) + 0)
#define ST_AhiL(T) stage16(Ahi + aoffL + (size_t)((((T) & 31) << 5)), ldsw + (((T) & 1) << 15) + 4096)
#define ST_AloE(T) stage16(Alo + aoffE + (size_t)((((T) & 31) << 5)), ldsw + (((T) & 1) << 15) + 8192)
#define ST_AloL(T) stage16(Alo + aoffL + (size_t)((((T) & 31) << 5)), ldsw + (((T) & 1) << 15) + 12288)
#define ST_BhiH0(T) stage16(Bhi + boff0 + ((size_t)((T) >> 5) << 18) + (size_t)((((T) & 31) << 5)), ldsw + (((T) & 1) << 15) + 16384)
#define ST_BhiH1(T) stage16(Bhi + boff1 + ((size_t)((T) >> 5) << 18) + (size_t)((((T) & 31) << 5)), ldsw + (((T) & 1) << 15) + 20480)
#define ST_BloH0(T) stage16(Blo + boff0 + ((size_t)((T) >> 5) << 18) + (size_t)((((T) & 31) << 5)), ldsw + (((T) & 1) << 15) + 24576)
#define ST_BloH1(T) stage16(Blo + boff1 + ((size_t)((T) >> 5) << 18) + (size_t)((((T) & 31) << 5)), ldsw + (((T) & 1) << 15) + 28672)

  // ---- fragment read offsets (within a buffer; stream base added at read) ----
  int a_off[8], b_off[4];
  #pragma unroll
  for (int mf = 0; mf < 8; ++mf) {
    int slot = wm * 64 + (mf & 3) * 16 + (l & 15);
    a_off[mf] = ((mf >> 2) * 4096) + slot * 32 + (((l >> 4) ^ ((slot >> 1) & 3)) << 3);
  }
  #pragma unroll
  for (int nf = 0; nf < 4; ++nf) {
    int r = wn * 64 + nf * 16 + (l & 15);
    b_off[nf] = r * 32 + (((l >> 4) ^ ((r >> 1) & 3)) << 3);
  }

  f32x4 acc[8][4];
  #pragma unroll
  for (int mf = 0; mf < 8; ++mf)
    #pragma unroll
    for (int nf = 0; nf < 4; ++nf) acc[mf][nf] = (f32x4){0.f, 0.f, 0.f, 0.f};

  const u16* const B0 = smem;
  const u16* const B1 = smem + 32768;
  short8 ah0, ah1, al0, al1, bh[4], bl[4];

#define LDA(BASE, MF) \
  ah0 = *(const short8*)((BASE) + a_off[MF]); \
  ah1 = *(const short8*)((BASE) + a_off[(MF) + 1]); \
  al0 = *(const short8*)((BASE) + 8192 + a_off[MF]); \
  al1 = *(const short8*)((BASE) + 8192 + a_off[(MF) + 1])

#define LDB(BASE) \
  { _Pragma("unroll") \
    for (int nf = 0; nf < 4; ++nf) { \
      bh[nf] = *(const short8*)((BASE) + 16384 + b_off[nf]); \
      bl[nf] = *(const short8*)((BASE) + 24576 + b_off[nf]); \
    } }

#define MMA2(MF) \
  __builtin_amdgcn_s_setprio(1); \
  { _Pragma("unroll") \
    for (int nf = 0; nf < 4; ++nf) { \
      acc[MF][nf] = __builtin_amdgcn_mfma_f32_16x16x32_bf16(ah0, bh[nf], acc[MF][nf], 0, 0, 0); \
      acc[MF][nf] = __builtin_amdgcn_mfma_f32_16x16x32_bf16(ah0, bl[nf], acc[MF][nf], 0, 0, 0); \
      acc[MF][nf] = __builtin_amdgcn_mfma_f32_16x16x32_bf16(al0, bh[nf], acc[MF][nf], 0, 0, 0); \
      acc[(MF) + 1][nf] = __builtin_amdgcn_mfma_f32_16x16x32_bf16(ah1, bh[nf], acc[(MF) + 1][nf], 0, 0, 0); \
      acc[(MF) + 1][nf] = __builtin_amdgcn_mfma_f32_16x16x32_bf16(ah1, bl[nf], acc[(MF) + 1][nf], 0, 0, 0); \
      acc[(MF) + 1][nf] = __builtin_amdgcn_mfma_f32_16x16x32_bf16(al1, bh[nf], acc[(MF) + 1][nf], 0, 0, 0); \
    } } \
  __builtin_amdgcn_s_setprio(0)

  // ---- prologue: stage tiles 0 and 1 (issue order mirrors steady-state ph2..ph8) ----
  ST_BhiH0(0); ST_BhiH1(0); ST_BloH0(0); ST_BloH1(0);
  ST_AhiE(0);  ST_AloE(0);  ST_AhiL(0);  ST_AloL(0);
  ST_BhiH0(1); ST_BhiH1(1); ST_BloH0(1); ST_BloH1(1);
  ST_AhiE(1);  ST_AloE(1);
  WAITV(8);                         // B(0)+A-E(0) landed; 8 newest stay in flight
  __builtin_amdgcn_s_barrier();
  FENCE();

  for (int it = 0; it < 64; ++it) {
    const bool last = (it == 63);
    const int T1 = 2 * it + 1, T2 = 2 * it + 2, T3 = 2 * it + 3;

    // ---- phase 1 (tile 2it, buf0): B frags + mf0,1 ----
    LDB(B0); LDA(B0, 0);
    ST_AhiL(T1); ST_AloL(T1);
    MMA2(0);
    __builtin_amdgcn_s_barrier(); FENCE();
    // ---- phase 2: mf2,3 ----
    LDA(B0, 2);
    if (!last) { ST_BhiH0(T2); ST_BhiH1(T2); }
    MMA2(2);
    if (last) { WAITV(8); } else { WAITV(10); }   // A-L(T0) landed
    __builtin_amdgcn_s_barrier(); FENCE();
    // ---- phase 3: mf4,5 ----
    LDA(B0, 4);
    if (!last) { ST_BloH0(T2); ST_BloH1(T2); }
    MMA2(4);
    __builtin_amdgcn_s_barrier(); FENCE();
    // ---- phase 4: mf6,7 ----
    LDA(B0, 6);
    if (!last) { ST_AhiE(T2); ST_AloE(T2); }
    MMA2(6);
    if (last) { WAITV(2); } else { WAITV(8); }    // B(T1)+A-E(T1) landed
    __builtin_amdgcn_s_barrier(); FENCE();
    // ---- phase 5 (tile 2it+1, buf1): B frags + mf0,1 ----
    LDB(B1); LDA(B1, 0);
    if (!last) { ST_AhiL(T2); ST_AloL(T2); }
    MMA2(0);
    __builtin_amdgcn_s_barrier(); FENCE();
    // ---- phase 6: mf2,3 ----
    LDA(B1, 2);
    if (!last) { ST_BhiH0(T3); ST_BhiH1(T3); }
    MMA2(2);
    if (last) { WAITV(0); } else { WAITV(10); }   // A-L(T1) landed
    __builtin_amdgcn_s_barrier(); FENCE();
    // ---- phase 7: mf4,5 ----
    LDA(B1, 4);
    if (!last) { ST_BloH0(T3); ST_BloH1(T3); }
    MMA2(4);
    __builtin_amdgcn_s_barrier(); FENCE();
    // ---- phase 8: mf6,7 ----
    LDA(B1, 6);
    if (!last) { ST_AhiE(T3); ST_AloE(T3); }
    MMA2(6);

    // ---- fold at the end of each 256-col group (it = 15,31,47,63) ----
    if ((it & 15) == 15) {
      const int t8 = it >> 4;
      const int nb = nyb * 1024 + t8 * 256 + wn * 64 + (l & 15);
      float b1v[4], w2v[4];
      #pragma unroll
      for (int nf = 0; nf < 4; ++nf) { b1v[nf] = b1[nb + nf * 16]; w2v[nf] = W2[nb + nf * 16]; }
      #pragma unroll
      for (int mf = 0; mf < 8; ++mf)
        #pragma unroll
        for (int r = 0; r < 4; ++r) {
          float p = 0.f;
          #pragma unroll
          for (int nf = 0; nf < 4; ++nf)
            p += fmaxf(acc[mf][nf][r] + b1v[nf], 0.f) * w2v[nf];
          p += __shfl_xor(p, 1); p += __shfl_xor(p, 2);
          p += __shfl_xor(p, 4); p += __shfl_xor(p, 8);
          if ((l & 15) == 0) {
            float* rp = red + ((wm * 128 + mf * 16 + (l >> 4) * 4 + r) << 2) + wn;
            if (t8 == 0) *rp = p; else *rp += p;
          }
        }
      #pragma unroll
      for (int mf = 0; mf < 8; ++mf)
        #pragma unroll
        for (int nf = 0; nf < 4; ++nf) acc[mf][nf] = (f32x4){0.f, 0.f, 0.f, 0.f};
    }

    WAITV(8);                       // B(T2)+A-E(T2) landed (no-op on fold/tail iters)
    __builtin_amdgcn_s_barrier(); FENCE();
  }

  __syncthreads();
  if (tid < 256) {
    const float* rp = red + (tid << 2);
    pl[(size_t)nyb * M_TOK + m0 + tid] = rp[0] + rp[1] + rp[2] + rp[3];
  }
}

// ---------------- fallback fp32 scorer (used only if ws too small) ----------------

__global__ __launch_bounds__(256) void scorer_kernel(
    const float* __restrict__ emb, const float* __restrict__ W1,
    const float* __restrict__ b1, const float* __restrict__ W2,
    const float* __restrict__ b2, float* __restrict__ pert) {
  __shared__ float As[16][68];
  __shared__ float Bs[16][132];
  __shared__ float red[64][17];

  const int tid = threadIdx.x;
  const int tx = tid & 15;
  const int ty = tid >> 4;
  const int m0 = blockIdx.x * 64;
  const int at = tid >> 2;
  const int ac = (tid & 3) << 2;
  const int br = tid >> 4;
  const int bc = (tid & 15) << 3;

  float logit[4] = {0.f, 0.f, 0.f, 0.f};

  for (int n0 = 0; n0 < H_DIM; n0 += 128) {
    float acc[4][8];
    #pragma unroll
    for (int i = 0; i < 4; i++)
      #pragma unroll
      for (int j = 0; j < 8; j++) acc[i][j] = 0.f;

    for (int k0 = 0; k0 < D_DIM; k0 += 16) {
      float4 av  = *(const float4*)(emb + (size_t)(m0 + at) * D_DIM + (k0 + ac));
      float4 bv0 = *(const float4*)(W1 + (size_t)(k0 + br) * H_DIM + (n0 + bc));
      float4 bv1 = *(const float4*)(W1 + (size_t)(k0 + br) * H_DIM + (n0 + bc) + 4);
      __syncthreads();
      As[ac + 0][at] = av.x; As[ac + 1][at] = av.y;
      As[ac + 2][at] = av.z; As[ac + 3][at] = av.w;
      *(float4*)&Bs[br][bc]     = bv0;
      *(float4*)&Bs[br][bc + 4] = bv1;
      __syncthreads();
      #pragma unroll
      for (int k = 0; k < 16; k++) {
        float4 a   = *(const float4*)&As[k][ty << 2];
        float4 b0  = *(const float4*)&Bs[k][tx << 3];
        float4 b1v = *(const float4*)&Bs[k][(tx << 3) + 4];
        float aa[4] = {a.x, a.y, a.z, a.w};
        float bb[8] = {b0.x, b0.y, b0.z, b0.w, b1v.x, b1v.y, b1v.z, b1v.w};
        #pragma unroll
        for (int i = 0; i < 4; i++)
          #pragma unroll
          for (int j = 0; j < 8; j++)
            acc[i][j] = fmaf(aa[i], bb[j], acc[i][j]);
      }
    }
    float4 c0 = *(const float4*)(b1 + n0 + (tx << 3));
    float4 c1 = *(const float4*)(b1 + n0 + (tx << 3) + 4);
    float4 w0 = *(const float4*)(W2 + n0 + (tx << 3));
    float4 w1 = *(const float4*)(W2 + n0 + (tx << 3) + 4);
    float cb[8] = {c0.x, c0.y, c0.z, c0.w, c1.x, c1.y, c1.z, c1.w};
    float wb[8] = {w0.x, w0.y, w0.z, w0.w, w1.x, w1.y, w1.z, w1.w};
    #pragma unroll
    for (int i = 0; i < 4; i++)
      #pragma unroll
      for (int j = 0; j < 8; j++) {
        float h = fmaxf(acc[i][j] + cb[j], 0.f);
        logit[i] = fmaf(h, wb[j], logit[i]);
      }
  }

  __syncthreads();
  #pragma unroll
  for (int i = 0; i < 4; i++) red[(ty << 2) + i][tx] = logit[i];
  __syncthreads();

  if (tid < 64) {
    float s = 0.f;
    #pragma unroll
    for (int x = 0; x < 16; x++) s += red[tid][x];
    s += b2[0];
    int t = m0 + tid;
    u32 r1a, r1b, r2a, r2b;
    jax_subkeys(r1a, r1b, r2a, r2b);
    pert[t] = s + gumbel_from_bits(jax_bits32(r2a, r2b, (u32)t));
  }
}

// ---------------- K3: binary-search top-k threshold -> hard mask ----------------

template <bool FROM_PL>
__device__ __forceinline__ void topk_body(const float* kl, const float* pl,
                                          const float* b2, float* mask,
                                          float* expk) {
  const int r = blockIdx.x;
  const int tid = threadIdx.x;
  const int w = tid >> 6, l = tid & 63;
  __shared__ int ksel_sh;
  __shared__ int cnt[2][4];

  u32 r1a, r1b, r2a, r2b;
  jax_subkeys(r1a, r1b, r2a, r2b);

  if (tid < 64) {
    float p = kl[l] + gumbel_from_bits(jax_bits32(r1a, r1b, (u32)l));
    u64 kkey = ((u64)ordf(p) << 32) | (unsigned)(63 - l);
    #pragma unroll
    for (int off = 32; off >= 1; off >>= 1) {
      u64 o = shflx64(kkey, off);
      if (o > kkey) kkey = o;
    }
    if (l == 0) ksel_sh = 64 - (int)(kkey & 0xffffffffu);
    if (r == 0) {
      float m = p;
      #pragma unroll
      for (int off = 32; off >= 1; off >>= 1) m = fmaxf(m, __shfl_xor(m, off));
      float e = expf(p - m);
      float s = e;
      #pragma unroll
      for (int off = 32; off >= 1; off >>= 1) s += __shfl_xor(s, off);
      float v = (e / s) * (float)(l + 1);
      #pragma unroll
      for (int off = 32; off >= 1; off >>= 1) v += __shfl_xor(v, off);
      if (l == 0) expk[0] = v;
    }
  }
  __syncthreads();
  const int k = ksel_sh;
  const float b2v = FROM_PL ? b2[0] : 0.f;

  u64 keys[16];
  #pragma unroll
  for (int j = 0; j < 16; j++) {
    int s = tid + (j << 8);
    int t = (r << 12) + s;
    float v;
    if (FROM_PL) {
      float acc = pl[t];
      #pragma unroll
      for (int q = 1; q < NSPLIT; ++q) acc += pl[(size_t)q * M_TOK + t];
      v = acc + b2v + gumbel_from_bits(jax_bits32(r2a, r2b, (u32)t));
    } else {
      v = mask[t];
    }
    keys[j] = ((u64)ordf(v) << 12) | (unsigned)s;
  }

  u64 lo = 0ull, hi = (1ull << 44) - 1ull;
  int it = 0;
  while (lo < hi) {
    const u64 mid = (lo + hi + 1ull) >> 1;
    int c = 0;
    #pragma unroll
    for (int j = 0; j < 16; j++) c += (keys[j] >= mid) ? 1 : 0;
    #pragma unroll
    for (int off = 32; off >= 1; off >>= 1) c += __shfl_xor(c, off);
    const int buf = it & 1;
    if (l == 0) cnt[buf][w] = c;
    __syncthreads();
    const int tot = cnt[buf][0] + cnt[buf][1] + cnt[buf][2] + cnt[buf][3];
    if (tot >= k) lo = mid; else hi = mid - 1ull;
    ++it;
  }
  const u64 thresh = lo;

  #pragma unroll
  for (int j = 0; j < 16; j++) {
    int s = tid + (j << 8);
    mask[(r << 12) + s] = (keys[j] >= thresh) ? 1.0f : 0.0f;
  }
}

__global__ __launch_bounds__(256) void topk_pl_kernel(const float* __restrict__ kl,
                                                      const float* __restrict__ pl,
                                                      const float* __restrict__ b2,
                                                      float* __restrict__ mask,
                                                      float* __restrict__ expk) {
  topk_body<true>(kl, pl, b2, mask, expk);
}

__global__ __launch_bounds__(256) void topk_kernel(const float* __restrict__ kl,
                                                   float* __restrict__ mask,
                                                   float* __restrict__ expk) {
  topk_body<false>(kl, nullptr, nullptr, mask, expk);
}

// ---------------- K4: filtered = emb * mask (2048 blocks x 16 tokens, deep MLP) ----------------

__global__ __launch_bounds__(256) void filter_kernel(const float* __restrict__ emb,
                                                     const float* __restrict__ mask,
                                                     float* __restrict__ out) {
  const int b = blockIdx.x;
  #pragma unroll
  for (int it = 0; it < 16; ++it) {
    const int t = b * 16 + it;
    const float mk = mask[t];
    const size_t base = (size_t)t * D_DIM + ((size_t)threadIdx.x << 2);
    float4 v = *(const float4*)(emb + base);
    *(float4*)(out + base) = make_float4(v.x * mk, v.y * mk, v.z * mk, v.w * mk);
  }
}

// ---------------- launcher ----------------

extern "C" void kernel_launch(void* const* d_in, const int* in_sizes, int n_in,
                              void* d_out, int out_size, void* d_ws, size_t ws_size,
                              hipStream_t stream) {
  const float* emb = (const float*)d_in[0];
  const float* W1  = (const float*)d_in[1];
  const float* b1  = (const float*)d_in[2];
  const float* W2  = (const float*)d_in[3];
  const float* b2  = (const float*)d_in[4];
  const float* kl  = (const float*)d_in[5];
  float* out  = (float*)d_out;
  float* mask = out + (size_t)M_TOK * D_DIM;
  float* expk = mask + M_TOK;

  const size_t ws_need = (size_t)H_DIM * D_DIM * 2 * 2 + (size_t)NSPLIT * M_TOK * 4;

  if (ws_size >= ws_need) {
    u16* Ahi = (u16*)d_out;                      // A split reuses output region
    u16* Alo = Ahi + (size_t)M_TOK * D_DIM;
    u16* Bhi = (u16*)d_ws;
    u16* Blo = Bhi + (size_t)H_DIM * D_DIM;
    float* pl = (float*)(Blo + (size_t)H_DIM * D_DIM);

    static bool attr_done = false;
    if (!attr_done) {
      hipFuncSetAttribute(reinterpret_cast<const void*>(scorer_mfma256),
                          hipFuncAttributeMaxDynamicSharedMemorySize, 135168);
      attr_done = true;
    }

    prep_kernel<<<PREP_A_BLOCKS + 2048, 256, 0, stream>>>(emb, Ahi, Alo, W1, Bhi, Blo);
    scorer_mfma256<<<256, 512, 135168, stream>>>(Ahi, Alo, Bhi, Blo, b1, W2, pl);
    topk_pl_kernel<<<B_BATCH, 256, 0, stream>>>(kl, pl, b2, mask, expk);
  } else {
    scorer_kernel<<<M_TOK / 64, 256, 0, stream>>>(emb, W1, b1, W2, b2, mask);
    topk_kernel<<<B_BATCH, 256, 0, stream>>>(kl, mask, expk);
  }

  filter_kernel<<<M_TOK / 16, 256, 0, stream>>>(emb, mask, out);
}

// Round 3
// 587.462 us; speedup vs baseline: 1.0484x; 1.0484x over previous
//
#include <hip/hip_runtime.h>
#include <stdint.h>

#define B_BATCH 8
#define S_SEQ   4096
#define D_DIM   1024
#define H_DIM   2048
#define M_TOK   (B_BATCH * S_SEQ)   // 32768
#define MAXK    64
#define NSPLIT  2                   // pl slices (H halves); one half per XCD parity

typedef unsigned int u32;
typedef unsigned short u16;
typedef unsigned long long u64;
typedef __attribute__((ext_vector_type(8))) short short8;   // 8 bf16 (4 VGPRs)
typedef __attribute__((ext_vector_type(4))) float f32x4;

#define GLOBAL_AS __attribute__((address_space(1)))
#define LDS_AS    __attribute__((address_space(3)))

// ---------------- JAX threefry2x32 (20 rounds), partitionable mode ----------------

#define TF_ROUND(x0, x1, r) { x0 += x1; x1 = ((x1 << r) | (x1 >> (32 - r))); x1 ^= x0; }

__device__ __forceinline__ void tf2x32(u32 k0, u32 k1, u32 x0, u32 x1, u32& o0, u32& o1) {
  u32 k2 = k0 ^ k1 ^ 0x1BD11BDAu;
  x0 += k0; x1 += k1;
  TF_ROUND(x0, x1, 13) TF_ROUND(x0, x1, 15) TF_ROUND(x0, x1, 26) TF_ROUND(x0, x1, 6)
  x0 += k1; x1 += k2 + 1u;
  TF_ROUND(x0, x1, 17) TF_ROUND(x0, x1, 29) TF_ROUND(x0, x1, 16) TF_ROUND(x0, x1, 24)
  x0 += k2; x1 += k0 + 2u;
  TF_ROUND(x0, x1, 13) TF_ROUND(x0, x1, 15) TF_ROUND(x0, x1, 26) TF_ROUND(x0, x1, 6)
  x0 += k0; x1 += k1 + 3u;
  TF_ROUND(x0, x1, 17) TF_ROUND(x0, x1, 29) TF_ROUND(x0, x1, 16) TF_ROUND(x0, x1, 24)
  x0 += k1; x1 += k2 + 4u;
  TF_ROUND(x0, x1, 13) TF_ROUND(x0, x1, 15) TF_ROUND(x0, x1, 26) TF_ROUND(x0, x1, 6)
  x0 += k2; x1 += k0 + 5u;
  o0 = x0; o1 = x1;
}

__device__ __forceinline__ void jax_subkeys(u32& r1a, u32& r1b, u32& r2a, u32& r2b) {
  tf2x32(0u, 42u, 0u, 0u, r1a, r1b);
  tf2x32(0u, 42u, 0u, 1u, r2a, r2b);
}

__device__ __forceinline__ u32 jax_bits32(u32 ka, u32 kb, u32 i) {
  u32 o0, o1;
  tf2x32(ka, kb, 0u, i, o0, o1);
  return o0 ^ o1;
}

__device__ __forceinline__ float jax_uniform_from_bits(u32 bits) {
  float f = __uint_as_float((bits >> 9) | 0x3f800000u) - 1.0f;
  float r = f + 1e-8f;
  return fmaxf(1e-8f, r);
}

__device__ __forceinline__ float gumbel_from_bits(u32 bits) {
  float u = jax_uniform_from_bits(bits);
  return -logf(-logf(u));
}

__device__ __forceinline__ u32 ordf(float v) {
  u32 b = __float_as_uint(v);
  return (b & 0x80000000u) ? ~b : (b | 0x80000000u);
}

__device__ __forceinline__ u64 shflx64(u64 v, int m) {
  unsigned lo = (unsigned)v, hi = (unsigned)(v >> 32);
  lo = (unsigned)__shfl_xor((int)lo, m);
  hi = (unsigned)__shfl_xor((int)hi, m);
  return ((u64)hi << 32) | lo;
}

// ---------------- bf16 split helpers ----------------

__device__ __forceinline__ u16 f2bf_rn(float x) {
  u32 u = __float_as_uint(x);
  u32 r = u + 0x7fffu + ((u >> 16) & 1u);
  return (u16)(r >> 16);
}

__device__ __forceinline__ void split1(float x, u16& h, u16& lo) {
  h = f2bf_rn(x);
  float hf = __uint_as_float(((u32)h) << 16);
  lo = f2bf_rn(x - hf);
}

// ---------------- LDS-image prep passes ----------------
// The scorer stages LDS tiles with global_load_lds (wave-uniform dest + lane*16B).
// Instead of strided 64B-per-row global reads (which double-fetch 128B lines and
// cost address VALU), prep writes the EXACT LDS byte image per (tile, K-step):
//   A_img[mt 128][kt 32][unit 4: hiE,hiL,loE,loL][wave 8][lane 64][8 u16]
//   B_img[nyb 2][t8 4][kt 32][unit 4: hiH0,hiH1,loH0,loH1][wave 8][lane 64][8 u16]
// XOR chunk swizzle is baked in here; scorer stage reads become linear-in-lane.

__global__ __launch_bounds__(256) void prep_a_img(const float* __restrict__ x,
                                                  u16* __restrict__ img) {
  const u32 t = blockIdx.x * 256 + threadIdx.x;   // 4M threads
  const int idx512 = (int)(t & 511);
  const int u1 = (int)((t >> 9) & 1);             // 0 = E rows, 1 = L rows
  const int kt = (int)((t >> 10) & 31);
  const int mt = (int)(t >> 15);
  const int w = idx512 >> 6, l = idx512 & 63;
  const int sig = w * 16 + (l >> 2);              // LDS row-slot
  const int r = sig + (sig & 64) + u1 * 64;       // A row within 256-row tile
  const int c = (l & 3) ^ ((sig >> 1) & 3);       // swizzled 8-elem chunk
  const float* src = x + (size_t)(mt * 256 + r) * D_DIM + kt * 32 + c * 8;
  float4 v0 = *(const float4*)src;
  float4 v1 = *(const float4*)(src + 4);
  union { u16 a[8]; short8 v; } H, L;
  split1(v0.x, H.a[0], L.a[0]); split1(v0.y, H.a[1], L.a[1]);
  split1(v0.z, H.a[2], L.a[2]); split1(v0.w, H.a[3], L.a[3]);
  split1(v1.x, H.a[4], L.a[4]); split1(v1.y, H.a[5], L.a[5]);
  split1(v1.z, H.a[6], L.a[6]); split1(v1.w, H.a[7], L.a[7]);
  u16* dhi = img + (size_t)(mt * 32 + kt) * 16384 + u1 * 4096 + idx512 * 8;
  *(short8*)dhi = H.v;                            // hi unit (0 or 1)
  *(short8*)(dhi + 8192) = L.v;                   // lo unit (2 or 3)
}

__global__ __launch_bounds__(256) void prep_b_img(const float* __restrict__ W1,
                                                  u16* __restrict__ img) {
  __shared__ float tile[64][33];
  const int tid = threadIdx.x;
  const int bid = blockIdx.x;                     // 1024 blocks: 64 n-tiles x 16 k-tiles
  const int n0 = (bid & 63) * 32, k0 = (bid >> 6) * 64;
  const int tx = tid & 31, ty = tid >> 5;         // ty 0..7
  #pragma unroll
  for (int rr = 0; rr < 8; ++rr)
    tile[ty + rr * 8][tx] = W1[(size_t)(k0 + ty + rr * 8) * H_DIM + n0 + tx];
  __syncthreads();
  const int nc = tid & 31, c8 = tid >> 5;         // c8: 2 k-tiles x 4 chunks
  const int ktl = c8 >> 2, cc = c8 & 3;
  const int n = n0 + nc;
  const int nyb = n >> 10, t8 = (n >> 8) & 3, rr_ = n & 255;
  const int hiU = rr_ >> 7;                       // H0 / H1 unit select
  const int sig = rr_ & 127;
  const int w_ = sig >> 4;
  const int lpos = (sig & 15) * 4 + (cc ^ ((sig >> 1) & 3));
  const int kt = (k0 >> 5) + ktl;
  union { u16 a[8]; short8 v; } H, L;
  #pragma unroll
  for (int j = 0; j < 8; ++j)
    split1(tile[ktl * 32 + cc * 8 + j][nc], H.a[j], L.a[j]);
  u16* d = img + (size_t)nyb * 2097152 + (size_t)(t8 * 32 + kt) * 16384
               + hiU * 4096 + w_ * 512 + lpos * 8;
  *(short8*)d = H.v;                              // hi unit (0/1)
  *(short8*)(d + 8192) = L.v;                     // lo unit (2/3)
}

// ---------------- K2: bf16x3 MFMA scorer, 256x256 tile, 8-phase counted-vmcnt ----------------
// Structure identical to R1 (8 waves 2m x 4n, BK=32, 2x64KB LDS dbuf + 4KB red,
// counted vmcnt(10)/(8), setprio, XOR swizzle); staging now reads the LDS-image
// buffers: per stage16, global addr = unit base + lane*16B (dense 128B lines).

__device__ __forceinline__ void stage16(const u16* g, u16* l) {
  __builtin_amdgcn_global_load_lds((const GLOBAL_AS u32*)g, (LDS_AS u32*)l, 16, 0, 0);
}

#define WAITV(N) asm volatile("s_waitcnt vmcnt(" #N ")" ::: "memory")
#define FENCE()  asm volatile("" ::: "memory")

__global__ __launch_bounds__(512, 2) void scorer_mfma256(
    const u16* __restrict__ Aimg, const u16* __restrict__ Bimg,
    const float* __restrict__ b1, const float* __restrict__ W2,
    float* __restrict__ pl) {
  extern __shared__ u16 smem[];                 // 2 x 32768 elems + 2048 elems (red)
  float* red = (float*)(smem + 65536);          // [256 rows][4 wn] f32

  const int tid = threadIdx.x;
  const int w = tid >> 6, l = tid & 63;
  const int wm = w >> 2, wn = w & 3;

  const int b = blockIdx.x;
  const int xcd = b & 7;
  const int nyb = xcd & 1;                      // H half for this XCD parity
  const int mt = (b >> 3) * 4 + (xcd >> 1);
  const int m0 = mt * 256;

  const u16* const Amt = Aimg + (size_t)mt * 524288;      // 32 kt x 16384 u16
  const u16* const Bny = Bimg + (size_t)nyb * 2097152;    // 4 t8 x 32 kt x 16384 u16
  const int lane16 = w * 512 + l * 8;           // per-lane offset within a unit (u16)
  u16* const ldsw = smem + w * 512;             // per-wave (uniform) dest within a unit

#define ST_A(T, U) stage16(Amt + (size_t)((((T) & 31) * 16384) + (U) * 4096) + lane16, \
                           ldsw + (((T) & 1) << 15) + (U) * 4096)
#define ST_B(T, U) stage16(Bny + (size_t)(((((T) >> 5) * 32 + ((T) & 31)) * 16384) + (U) * 4096) + lane16, \
                           ldsw + (((T) & 1) << 15) + 16384 + (U) * 4096)

  // ---- fragment read offsets (within a buffer; stream base added at read) ----
  int a_off[8], b_off[4];
  #pragma unroll
  for (int mf = 0; mf < 8; ++mf) {
    int slot = wm * 64 + (mf & 3) * 16 + (l & 15);
    a_off[mf] = ((mf >> 2) * 4096) + slot * 32 + (((l >> 4) ^ ((slot >> 1) & 3)) << 3);
  }
  #pragma unroll
  for (int nf = 0; nf < 4; ++nf) {
    int r = wn * 64 + nf * 16 + (l & 15);
    b_off[nf] = r * 32 + (((l >> 4) ^ ((r >> 1) & 3)) << 3);
  }

  f32x4 acc[8][4];
  #pragma unroll
  for (int mf = 0; mf < 8; ++mf)
    #pragma unroll
    for (int nf = 0; nf < 4; ++nf) acc[mf][nf] = (f32x4){0.f, 0.f, 0.f, 0.f};

  const u16* const B0 = smem;
  const u16* const B1 = smem + 32768;
  short8 ah0, ah1, al0, al1, bh[4], bl[4];

#define LDA(BASE, MF) \
  ah0 = *(const short8*)((BASE) + a_off[MF]); \
  ah1 = *(const short8*)((BASE) + a_off[(MF) + 1]); \
  al0 = *(const short8*)((BASE) + 8192 + a_off[MF]); \
  al1 = *(const short8*)((BASE) + 8192 + a_off[(MF) + 1])

#define LDB(BASE) \
  { _Pragma("unroll") \
    for (int nf = 0; nf < 4; ++nf) { \
      bh[nf] = *(const short8*)((BASE) + 16384 + b_off[nf]); \
      bl[nf] = *(const short8*)((BASE) + 24576 + b_off[nf]); \
    } }

#define MMA2(MF) \
  __builtin_amdgcn_s_setprio(1); \
  { _Pragma("unroll") \
    for (int nf = 0; nf < 4; ++nf) { \
      acc[MF][nf] = __builtin_amdgcn_mfma_f32_16x16x32_bf16(ah0, bh[nf], acc[MF][nf], 0, 0, 0); \
      acc[MF][nf] = __builtin_amdgcn_mfma_f32_16x16x32_bf16(ah0, bl[nf], acc[MF][nf], 0, 0, 0); \
      acc[MF][nf] = __builtin_amdgcn_mfma_f32_16x16x32_bf16(al0, bh[nf], acc[MF][nf], 0, 0, 0); \
      acc[(MF) + 1][nf] = __builtin_amdgcn_mfma_f32_16x16x32_bf16(ah1, bh[nf], acc[(MF) + 1][nf], 0, 0, 0); \
      acc[(MF) + 1][nf] = __builtin_amdgcn_mfma_f32_16x16x32_bf16(ah1, bl[nf], acc[(MF) + 1][nf], 0, 0, 0); \
      acc[(MF) + 1][nf] = __builtin_amdgcn_mfma_f32_16x16x32_bf16(al1, bh[nf], acc[(MF) + 1][nf], 0, 0, 0); \
    } } \
  __builtin_amdgcn_s_setprio(0)

  // ---- prologue: stage tiles 0 and 1 (issue order mirrors steady-state ph2..ph8) ----
  ST_B(0, 0); ST_B(0, 1); ST_B(0, 2); ST_B(0, 3);
  ST_A(0, 0); ST_A(0, 2); ST_A(0, 1); ST_A(0, 3);
  ST_B(1, 0); ST_B(1, 1); ST_B(1, 2); ST_B(1, 3);
  ST_A(1, 0); ST_A(1, 2);
  WAITV(8);                         // B(0)+A-E(0) landed; 8 newest stay in flight
  __builtin_amdgcn_s_barrier();
  FENCE();

  for (int it = 0; it < 64; ++it) {
    const bool last = (it == 63);
    const int T1 = 2 * it + 1, T2 = 2 * it + 2, T3 = 2 * it + 3;

    // ---- phase 1 (tile 2it, buf0): B frags + mf0,1 ----
    LDB(B0); LDA(B0, 0);
    ST_A(T1, 1); ST_A(T1, 3);
    MMA2(0);
    __builtin_amdgcn_s_barrier(); FENCE();
    // ---- phase 2: mf2,3 ----
    LDA(B0, 2);
    if (!last) { ST_B(T2, 0); ST_B(T2, 1); }
    MMA2(2);
    if (last) { WAITV(8); } else { WAITV(10); }   // A-L(T0) landed
    __builtin_amdgcn_s_barrier(); FENCE();
    // ---- phase 3: mf4,5 ----
    LDA(B0, 4);
    if (!last) { ST_B(T2, 2); ST_B(T2, 3); }
    MMA2(4);
    __builtin_amdgcn_s_barrier(); FENCE();
    // ---- phase 4: mf6,7 ----
    LDA(B0, 6);
    if (!last) { ST_A(T2, 0); ST_A(T2, 2); }
    MMA2(6);
    if (last) { WAITV(2); } else { WAITV(8); }    // B(T1)+A-E(T1) landed
    __builtin_amdgcn_s_barrier(); FENCE();
    // ---- phase 5 (tile 2it+1, buf1): B frags + mf0,1 ----
    LDB(B1); LDA(B1, 0);
    if (!last) { ST_A(T2, 1); ST_A(T2, 3); }
    MMA2(0);
    __builtin_amdgcn_s_barrier(); FENCE();
    // ---- phase 6: mf2,3 ----
    LDA(B1, 2);
    if (!last) { ST_B(T3, 0); ST_B(T3, 1); }
    MMA2(2);
    if (last) { WAITV(0); } else { WAITV(10); }   // A-L(T1) landed
    __builtin_amdgcn_s_barrier(); FENCE();
    // ---- phase 7: mf4,5 ----
    LDA(B1, 4);
    if (!last) { ST_B(T3, 2); ST_B(T3, 3); }
    MMA2(4);
    __builtin_amdgcn_s_barrier(); FENCE();
    // ---- phase 8: mf6,7 ----
    LDA(B1, 6);
    if (!last) { ST_A(T3, 0); ST_A(T3, 2); }
    MMA2(6);

    // ---- fold at the end of each 256-col group (it = 15,31,47,63) ----
    if ((it & 15) == 15) {
      const int t8 = it >> 4;
      const int nb = nyb * 1024 + t8 * 256 + wn * 64 + (l & 15);
      float b1v[4], w2v[4];
      #pragma unroll
      for (int nf = 0; nf < 4; ++nf) { b1v[nf] = b1[nb + nf * 16]; w2v[nf] = W2[nb + nf * 16]; }
      #pragma unroll
      for (int mf = 0; mf < 8; ++mf)
        #pragma unroll
        for (int r = 0; r < 4; ++r) {
          float p = 0.f;
          #pragma unroll
          for (int nf = 0; nf < 4; ++nf)
            p += fmaxf(acc[mf][nf][r] + b1v[nf], 0.f) * w2v[nf];
          p += __shfl_xor(p, 1); p += __shfl_xor(p, 2);
          p += __shfl_xor(p, 4); p += __shfl_xor(p, 8);
          if ((l & 15) == 0) {
            float* rp = red + ((wm * 128 + mf * 16 + (l >> 4) * 4 + r) << 2) + wn;
            if (t8 == 0) *rp = p; else *rp += p;
          }
        }
      #pragma unroll
      for (int mf = 0; mf < 8; ++mf)
        #pragma unroll
        for (int nf = 0; nf < 4; ++nf) acc[mf][nf] = (f32x4){0.f, 0.f, 0.f, 0.f};
    }

    WAITV(8);                       // B(T2)+A-E(T2) landed (no-op on fold/tail iters)
    __builtin_amdgcn_s_barrier(); FENCE();
  }

  __syncthreads();
  if (tid < 256) {
    const float* rp = red + (tid << 2);
    pl[(size_t)nyb * M_TOK + m0 + tid] = rp[0] + rp[1] + rp[2] + rp[3];
  }
}

// ---------------- fallback fp32 scorer (used only if ws too small) ----------------

__global__ __launch_bounds__(256) void scorer_kernel(
    const float* __restrict__ emb, const float* __restrict__ W1,
    const float* __restrict__ b1, const float* __restrict__ W2,
    const float* __restrict__ b2, float* __restrict__ pert) {
  __shared__ float As[16][68];
  __shared__ float Bs[16][132];
  __shared__ float red[64][17];

  const int tid = threadIdx.x;
  const int tx = tid & 15;
  const int ty = tid >> 4;
  const int m0 = blockIdx.x * 64;
  const int at = tid >> 2;
  const int ac = (tid & 3) << 2;
  const int br = tid >> 4;
  const int bc = (tid & 15) << 3;

  float logit[4] = {0.f, 0.f, 0.f, 0.f};

  for (int n0 = 0; n0 < H_DIM; n0 += 128) {
    float acc[4][8];
    #pragma unroll
    for (int i = 0; i < 4; i++)
      #pragma unroll
      for (int j = 0; j < 8; j++) acc[i][j] = 0.f;

    for (int k0 = 0; k0 < D_DIM; k0 += 16) {
      float4 av  = *(const float4*)(emb + (size_t)(m0 + at) * D_DIM + (k0 + ac));
      float4 bv0 = *(const float4*)(W1 + (size_t)(k0 + br) * H_DIM + (n0 + bc));
      float4 bv1 = *(const float4*)(W1 + (size_t)(k0 + br) * H_DIM + (n0 + bc) + 4);
      __syncthreads();
      As[ac + 0][at] = av.x; As[ac + 1][at] = av.y;
      As[ac + 2][at] = av.z; As[ac + 3][at] = av.w;
      *(float4*)&Bs[br][bc]     = bv0;
      *(float4*)&Bs[br][bc + 4] = bv1;
      __syncthreads();
      #pragma unroll
      for (int k = 0; k < 16; k++) {
        float4 a   = *(const float4*)&As[k][ty << 2];
        float4 b0  = *(const float4*)&Bs[k][tx << 3];
        float4 b1v = *(const float4*)&Bs[k][(tx << 3) + 4];
        float aa[4] = {a.x, a.y, a.z, a.w};
        float bb[8] = {b0.x, b0.y, b0.z, b0.w, b1v.x, b1v.y, b1v.z, b1v.w};
        #pragma unroll
        for (int i = 0; i < 4; i++)
          #pragma unroll
          for (int j = 0; j < 8; j++)
            acc[i][j] = fmaf(aa[i], bb[j], acc[i][j]);
      }
    }
    float4 c0 = *(const float4*)(b1 + n0 + (tx << 3));
    float4 c1 = *(const float4*)(b1 + n0 + (tx << 3) + 4);
    float4 w0 = *(const float4*)(W2 + n0 + (tx << 3));
    float4 w1 = *(const float4*)(W2 + n0 + (tx << 3) + 4);
    float cb[8] = {c0.x, c0.y, c0.z, c0.w, c1.x, c1.y, c1.z, c1.w};
    float wb[8] = {w0.x, w0.y, w0.z, w0.w, w1.x, w1.y, w1.z, w1.w};
    #pragma unroll
    for (int i = 0; i < 4; i++)
      #pragma unroll
      for (int j = 0; j < 8; j++) {
        float h = fmaxf(acc[i][j] + cb[j], 0.f);
        logit[i] = fmaf(h, wb[j], logit[i]);
      }
  }

  __syncthreads();
  #pragma unroll
  for (int i = 0; i < 4; i++) red[(ty << 2) + i][tx] = logit[i];
  __syncthreads();

  if (tid < 64) {
    float s = 0.f;
    #pragma unroll
    for (int x = 0; x < 16; x++) s += red[tid][x];
    s += b2[0];
    int t = m0 + tid;
    u32 r1a, r1b, r2a, r2b;
    jax_subkeys(r1a, r1b, r2a, r2b);
    pert[t] = s + gumbel_from_bits(jax_bits32(r2a, r2b, (u32)t));
  }
}

// ---------------- K3: binary-search top-k threshold -> hard mask ----------------

template <bool FROM_PL>
__device__ __forceinline__ void topk_body(const float* kl, const float* pl,
                                          const float* b2, float* mask,
                                          float* expk) {
  const int r = blockIdx.x;
  const int tid = threadIdx.x;
  const int w = tid >> 6, l = tid & 63;
  __shared__ int ksel_sh;
  __shared__ int cnt[2][4];

  u32 r1a, r1b, r2a, r2b;
  jax_subkeys(r1a, r1b, r2a, r2b);

  if (tid < 64) {
    float p = kl[l] + gumbel_from_bits(jax_bits32(r1a, r1b, (u32)l));
    u64 kkey = ((u64)ordf(p) << 32) | (unsigned)(63 - l);
    #pragma unroll
    for (int off = 32; off >= 1; off >>= 1) {
      u64 o = shflx64(kkey, off);
      if (o > kkey) kkey = o;
    }
    if (l == 0) ksel_sh = 64 - (int)(kkey & 0xffffffffu);
    if (r == 0) {
      float m = p;
      #pragma unroll
      for (int off = 32; off >= 1; off >>= 1) m = fmaxf(m, __shfl_xor(m, off));
      float e = expf(p - m);
      float s = e;
      #pragma unroll
      for (int off = 32; off >= 1; off >>= 1) s += __shfl_xor(s, off);
      float v = (e / s) * (float)(l + 1);
      #pragma unroll
      for (int off = 32; off >= 1; off >>= 1) v += __shfl_xor(v, off);
      if (l == 0) expk[0] = v;
    }
  }
  __syncthreads();
  const int k = ksel_sh;
  const float b2v = FROM_PL ? b2[0] : 0.f;

  u64 keys[16];
  #pragma unroll
  for (int j = 0; j < 16; j++) {
    int s = tid + (j << 8);
    int t = (r << 12) + s;
    float v;
    if (FROM_PL) {
      float acc = pl[t];
      #pragma unroll
      for (int q = 1; q < NSPLIT; ++q) acc += pl[(size_t)q * M_TOK + t];
      v = acc + b2v + gumbel_from_bits(jax_bits32(r2a, r2b, (u32)t));
    } else {
      v = mask[t];
    }
    keys[j] = ((u64)ordf(v) << 12) | (unsigned)s;
  }

  u64 lo = 0ull, hi = (1ull << 44) - 1ull;
  int it = 0;
  while (lo < hi) {
    const u64 mid = (lo + hi + 1ull) >> 1;
    int c = 0;
    #pragma unroll
    for (int j = 0; j < 16; j++) c += (keys[j] >= mid) ? 1 : 0;
    #pragma unroll
    for (int off = 32; off >= 1; off >>= 1) c += __shfl_xor(c, off);
    const int buf = it & 1;
    if (l == 0) cnt[buf][w] = c;
    __syncthreads();
    const int tot = cnt[buf][0] + cnt[buf][1] + cnt[buf][2] + cnt[buf][3];
    if (tot >= k) lo = mid; else hi = mid - 1ull;
    ++it;
  }
  const u64 thresh = lo;

  #pragma unroll
  for (int j = 0; j < 16; j++) {
    int s = tid + (j << 8);
    mask[(r << 12) + s] = (keys[j] >= thresh) ? 1.0f : 0.0f;
  }
}

__global__ __launch_bounds__(256) void topk_pl_kernel(const float* __restrict__ kl,
                                                      const float* __restrict__ pl,
                                                      const float* __restrict__ b2,
                                                      float* __restrict__ mask,
                                                      float* __restrict__ expk) {
  topk_body<true>(kl, pl, b2, mask, expk);
}

__global__ __launch_bounds__(256) void topk_kernel(const float* __restrict__ kl,
                                                   float* __restrict__ mask,
                                                   float* __restrict__ expk) {
  topk_body<false>(kl, nullptr, nullptr, mask, expk);
}

// ---------------- K4: filtered = emb * mask (r5-proven one-token blocks) ----------------

__global__ __launch_bounds__(256) void filter_kernel(const float* __restrict__ emb,
                                                     const float* __restrict__ mask,
                                                     float* __restrict__ out) {
  const int t = blockIdx.x;
  const float mk = mask[t];
  const size_t base = (size_t)t * D_DIM + ((size_t)threadIdx.x << 2);
  float4 v = *(const float4*)(emb + base);
  *(float4*)(out + base) = make_float4(v.x * mk, v.y * mk, v.z * mk, v.w * mk);
}

// ---------------- launcher ----------------

extern "C" void kernel_launch(void* const* d_in, const int* in_sizes, int n_in,
                              void* d_out, int out_size, void* d_ws, size_t ws_size,
                              hipStream_t stream) {
  const float* emb = (const float*)d_in[0];
  const float* W1  = (const float*)d_in[1];
  const float* b1  = (const float*)d_in[2];
  const float* W2  = (const float*)d_in[3];
  const float* b2  = (const float*)d_in[4];
  const float* kl  = (const float*)d_in[5];
  float* out  = (float*)d_out;
  float* mask = out + (size_t)M_TOK * D_DIM;
  float* expk = mask + M_TOK;

  const size_t ws_need = (size_t)H_DIM * D_DIM * 2 * 2 + (size_t)NSPLIT * M_TOK * 4;

  if (ws_size >= ws_need) {
    u16* Aimg = (u16*)d_out;                     // A image reuses output region (128MB)
    u16* Bimg = (u16*)d_ws;                      // B image (8MB)
    float* pl = (float*)(Bimg + (size_t)2 * H_DIM * D_DIM);

    static bool attr_done = false;
    if (!attr_done) {
      hipFuncSetAttribute(reinterpret_cast<const void*>(scorer_mfma256),
                          hipFuncAttributeMaxDynamicSharedMemorySize, 135168);
      attr_done = true;
    }

    prep_a_img<<<16384, 256, 0, stream>>>(emb, Aimg);
    prep_b_img<<<1024, 256, 0, stream>>>(W1, Bimg);
    scorer_mfma256<<<256, 512, 135168, stream>>>(Aimg, Bimg, b1, W2, pl);
    topk_pl_kernel<<<B_BATCH, 256, 0, stream>>>(kl, pl, b2, mask, expk);
  } else {
    scorer_kernel<<<M_TOK / 64, 256, 0, stream>>>(emb, W1, b1, W2, b2, mask);
    topk_kernel<<<B_BATCH, 256, 0, stream>>>(kl, mask, expk);
  }

  filter_kernel<<<M_TOK, 256, 0, stream>>>(emb, mask, out);
}